// Round 1
// 1188.668 us; speedup vs baseline: 1.1938x; 1.1938x over previous
//
#include <hip/hip_runtime.h>
#include <hip/hip_bf16.h>

// Problem constants (B=2, T=2048 -> BT=4096 tokens)
#define CC   128
#define EE   16
#define KBB  32
#define VV   50257
#define BT   4096
#define TB   8      // tokens per block

typedef __bf16 bf16x8 __attribute__((ext_vector_type(8)));
typedef float  f32x4  __attribute__((ext_vector_type(4)));

__device__ inline unsigned short f2b(float f) {
    unsigned int i = __builtin_bit_cast(unsigned int, f);
    unsigned int r = (i + 0x7fffu + ((i >> 16) & 1u)) >> 16;   // RNE
    return (unsigned short)r;
}

__device__ inline float dot4(const float4 a, const float4 b) {
    return a.x * b.x + a.y * b.y + a.z * b.z + a.w * b.w;
}

// Batched token kernel: 8 tokens per 256-thread block (grid = 512 = 2 blocks/CU).
// All weights/experts are loaded once per 8 tokens; LN/softmax reductions are
// wave-internal shfl_xor (32- or 16-lane groups); 9 barriers per 8 tokens.
__global__ __launch_bounds__(256)
void token_kernel(const int* __restrict__ ids,
                  const float* __restrict__ emb,
                  const float* __restrict__ router,
                  const float* __restrict__ k_ex,
                  const float* __restrict__ v_ex,
                  const float* __restrict__ st_k,
                  const float* __restrict__ st_v,
                  const float* __restrict__ kv_gate,
                  const float* __restrict__ Wq,
                  const float* __restrict__ Wo,
                  const float* __restrict__ Wmlp,
                  const float* __restrict__ bmlp,
                  const float* __restrict__ g1,
                  const float* __restrict__ b1,
                  const float* __restrict__ g2,
                  const float* __restrict__ b2v,
                  float* __restrict__ gate_out,
                  unsigned short* __restrict__ xf_out)
{
    __shared__ __align__(16) float s_xln[TB][CC];      // 4 KB
    __shared__ __align__(16) float s_x0 [TB][CC];      // 4 KB
    __shared__ __align__(16) float s_q  [TB][CC];      // 4 KB
    __shared__ __align__(16) float s_mw [TB * EE * KBB]; // 16 KB: m as [t][512], then w as [r][8]
    __shared__ __align__(16) float s_part[8][TB][CC];  // 16 KB: v-mix partials per row-group
    __shared__ __align__(16) float s_ao [TB][CC];      // 4 KB: attn out, later aliased as y (LN2 out)
    __shared__ __align__(16) float s_xr [TB][CC];      // 4 KB: residual after Wo
    __shared__ float s_rw[TB][EE];                     // router weights
    __shared__ float s_at[TB][KBB];                    // attn weights

    const int tid = threadIdx.x;
    const int t0g = blockIdx.x * TB;

    const float gg = 1.f / (1.f + expf(-kv_gate[0]));

    // channel-major mapping (32 lanes per token): token tA, channels cA..cA+3
    const int tA = tid >> 5;
    const int cA = (tid & 31) * 4;
    // matvec mapping: output dim dV, 4 tokens starting at tgV
    const int dV = tid & 127;
    const int tgV = (tid >> 7) * 4;

    // ---- Phase A: embed + LN1 (reduction over the token's 32 lanes) ----
    {
        const int id = ids[t0g + tA];
        const float4 x0 = *reinterpret_cast<const float4*>(emb + (size_t)id * CC + cA);
        float s = x0.x + x0.y + x0.z + x0.w;
#pragma unroll
        for (int mk = 1; mk < 32; mk <<= 1) s += __shfl_xor(s, mk, 64);
        const float mu = s * (1.f / CC);
        float4 d;
        d.x = x0.x - mu; d.y = x0.y - mu; d.z = x0.z - mu; d.w = x0.w - mu;
        float v = d.x * d.x + d.y * d.y + d.z * d.z + d.w * d.w;
#pragma unroll
        for (int mk = 1; mk < 32; mk <<= 1) v += __shfl_xor(v, mk, 64);
        const float rs = rsqrtf(v * (1.f / CC) + 1e-5f);
        const float4 gv = *reinterpret_cast<const float4*>(g1 + cA);
        const float4 bv = *reinterpret_cast<const float4*>(b1 + cA);
        float4 xl;
        xl.x = d.x * rs * gv.x + bv.x;
        xl.y = d.y * rs * gv.y + bv.y;
        xl.z = d.z * rs * gv.z + bv.z;
        xl.w = d.w * rs * gv.w + bv.w;
        *reinterpret_cast<float4*>(&s_xln[tA][cA]) = xl;
        *reinterpret_cast<float4*>(&s_x0[tA][cA]) = x0;
    }
    __syncthreads();

    // ---- Phase B: gate logits + router softmax (16 e-lanes x 2 c-halves per token) ----
    {
        const int e = tid & 15;
        const int half = (tid >> 4) & 1;
        const float* rp = router + e * CC + half * 64;
        const float* xp = &s_xln[tA][half * 64];
        float acc = 0.f;
#pragma unroll
        for (int c = 0; c < 64; c += 4)
            acc += dot4(*reinterpret_cast<const float4*>(rp + c),
                        *reinterpret_cast<const float4*>(xp + c));
        acc += __shfl_xor(acc, 16, 64);            // combine c-halves
        if (half == 0) gate_out[(size_t)(t0g + tA) * EE + e] = acc;
        float mx = acc;
#pragma unroll
        for (int mk = 1; mk < 16; mk <<= 1) mx = fmaxf(mx, __shfl_xor(mx, mk, 64));
        const float ex = expf(acc - mx);
        float ss = ex;
#pragma unroll
        for (int mk = 1; mk < 16; mk <<= 1) ss += __shfl_xor(ss, mk, 64);
        if (half == 0) s_rw[tA][e] = ex / ss;
    }

    // ---- Phase D: q[t][d] = xln[t] . Wq[d] (one weight row for 4 tokens) ----
    {
        const float* wp = Wq + dV * CC;
        float a0 = 0.f, a1 = 0.f, a2 = 0.f, a3 = 0.f;
#pragma unroll 8
        for (int c = 0; c < CC; c += 4) {
            const float4 w = *reinterpret_cast<const float4*>(wp + c);
            a0 += dot4(w, *reinterpret_cast<const float4*>(&s_xln[tgV + 0][c]));
            a1 += dot4(w, *reinterpret_cast<const float4*>(&s_xln[tgV + 1][c]));
            a2 += dot4(w, *reinterpret_cast<const float4*>(&s_xln[tgV + 2][c]));
            a3 += dot4(w, *reinterpret_cast<const float4*>(&s_xln[tgV + 3][c]));
        }
        s_q[tgV + 0][dV] = a0;
        s_q[tgV + 1][dV] = a1;
        s_q[tgV + 2][dV] = a2;
        s_q[tgV + 3][dV] = a3;
    }
    __syncthreads();

    // ---- Phase E: m[t][r] = q[t] . k_ex[r]  (2 rows x 8 tokens per thread) ----
    {
        const int r0 = tid * 2;
        const float* k0p = k_ex + (size_t)r0 * CC;
        const float* k1p = k0p + CC;
        float acc0[TB] = {0.f, 0.f, 0.f, 0.f, 0.f, 0.f, 0.f, 0.f};
        float acc1[TB] = {0.f, 0.f, 0.f, 0.f, 0.f, 0.f, 0.f, 0.f};
#pragma unroll 4
        for (int c = 0; c < CC; c += 4) {
            const float4 k0 = *reinterpret_cast<const float4*>(k0p + c);
            const float4 k1 = *reinterpret_cast<const float4*>(k1p + c);
#pragma unroll
            for (int t = 0; t < TB; t++) {
                const float4 q = *reinterpret_cast<const float4*>(&s_q[t][c]);
                acc0[t] += dot4(k0, q);
                acc1[t] += dot4(k1, q);
            }
        }
#pragma unroll
        for (int t = 0; t < TB; t++) {
            s_mw[t * (EE * KBB) + r0]     = acc0[t];
            s_mw[t * (EE * KBB) + r0 + 1] = acc1[t];
        }
    }
    __syncthreads();

    // ---- Phase F: scores + softmax over KB (32 k-lanes per token) ----
    {
        const int k = tid & 31;
        float accs = 0.f;
#pragma unroll
        for (int e = 0; e < EE; e++)
            accs += s_rw[tA][e] * s_mw[tA * (EE * KBB) + e * KBB + k];
        const float* kp = st_k + k * CC;
        float accst = 0.f;
#pragma unroll 8
        for (int c = 0; c < CC; c += 4)
            accst += dot4(*reinterpret_cast<const float4*>(kp + c),
                          *reinterpret_cast<const float4*>(&s_q[tA][c]));
        const float sc = (gg * accs + (1.f - gg) * accst) * 0.08838834764831845f; // 1/sqrt(128)
        float mx = sc;
#pragma unroll
        for (int mk = 1; mk < 32; mk <<= 1) mx = fmaxf(mx, __shfl_xor(mx, mk, 64));
        const float ex = expf(sc - mx);
        float ss = ex;
#pragma unroll
        for (int mk = 1; mk < 32; mk <<= 1) ss += __shfl_xor(ss, mk, 64);
        s_at[tA][k] = ex / ss;
    }
    __syncthreads();

    // ---- Phase G: w[r][t] = gg * rw[t][e(r)] * at[t][k(r)] (transposed, gg folded) ----
    {
#pragma unroll
        for (int i = 0; i < (TB * EE * KBB) / 256; i++) {   // 16
            const int idx = tid + i * 256;
            const int r = idx >> 3;
            const int t = idx & 7;
            s_mw[r * TB + t] = gg * s_rw[t][r >> 5] * s_at[t][r & 31];
        }
    }
    __syncthreads();

    // ---- Phase H: v-mix partials: 64 rows per thread-group, 8 tokens x 4 ch per thread ----
    {
        const int g = tid >> 5;
        const int rbase = g * 64;
        f32x4 acc0 = {0.f, 0.f, 0.f, 0.f}, acc1 = acc0, acc2 = acc0, acc3 = acc0;
        f32x4 acc4 = acc0, acc5 = acc0, acc6 = acc0, acc7 = acc0;
#pragma unroll 2
        for (int r = 0; r < 64; r++) {
            const f32x4 v = *reinterpret_cast<const f32x4*>(
                v_ex + (size_t)(rbase + r) * CC + cA);
            const float4 w0 = *reinterpret_cast<const float4*>(&s_mw[(rbase + r) * TB]);
            const float4 w1 = *reinterpret_cast<const float4*>(&s_mw[(rbase + r) * TB + 4]);
            acc0 += w0.x * v; acc1 += w0.y * v; acc2 += w0.z * v; acc3 += w0.w * v;
            acc4 += w1.x * v; acc5 += w1.y * v; acc6 += w1.z * v; acc7 += w1.w * v;
        }
        *reinterpret_cast<f32x4*>(&s_part[g][0][cA]) = acc0;
        *reinterpret_cast<f32x4*>(&s_part[g][1][cA]) = acc1;
        *reinterpret_cast<f32x4*>(&s_part[g][2][cA]) = acc2;
        *reinterpret_cast<f32x4*>(&s_part[g][3][cA]) = acc3;
        *reinterpret_cast<f32x4*>(&s_part[g][4][cA]) = acc4;
        *reinterpret_cast<f32x4*>(&s_part[g][5][cA]) = acc5;
        *reinterpret_cast<f32x4*>(&s_part[g][6][cA]) = acc6;
        *reinterpret_cast<f32x4*>(&s_part[g][7][cA]) = acc7;
    }
    __syncthreads();

    // ---- Phase I: reduce partials + static V + combine -> s_ao ----
    {
        f32x4 pa = {0.f, 0.f, 0.f, 0.f};
#pragma unroll
        for (int g = 0; g < 8; g++)
            pa += *reinterpret_cast<const f32x4*>(&s_part[g][tA][cA]);
        f32x4 stat = {0.f, 0.f, 0.f, 0.f};
#pragma unroll 8
        for (int k = 0; k < KBB; k++) {
            const f32x4 sv = *reinterpret_cast<const f32x4*>(st_v + k * CC + cA);
            stat += s_at[tA][k] * sv;
        }
        const f32x4 ao = pa + (1.f - gg) * stat;    // pa already gg-scaled via w
        *reinterpret_cast<f32x4*>(&s_ao[tA][cA]) = ao;
    }
    __syncthreads();

    // ---- Phase M: Wo projection + residual -> s_xr ----
    {
        const float* wp = Wo + dV * CC;
        float a0 = 0.f, a1 = 0.f, a2 = 0.f, a3 = 0.f;
#pragma unroll 8
        for (int c = 0; c < CC; c += 4) {
            const float4 w = *reinterpret_cast<const float4*>(wp + c);
            a0 += dot4(w, *reinterpret_cast<const float4*>(&s_ao[tgV + 0][c]));
            a1 += dot4(w, *reinterpret_cast<const float4*>(&s_ao[tgV + 1][c]));
            a2 += dot4(w, *reinterpret_cast<const float4*>(&s_ao[tgV + 2][c]));
            a3 += dot4(w, *reinterpret_cast<const float4*>(&s_ao[tgV + 3][c]));
        }
        s_xr[tgV + 0][dV] = s_x0[tgV + 0][dV] + a0;
        s_xr[tgV + 1][dV] = s_x0[tgV + 1][dV] + a1;
        s_xr[tgV + 2][dV] = s_x0[tgV + 2][dV] + a2;
        s_xr[tgV + 3][dV] = s_x0[tgV + 3][dV] + a3;
    }
    __syncthreads();

    // ---- Phase N: LN2 -> y (aliased into s_ao) ----
    {
        const float4 xr = *reinterpret_cast<const float4*>(&s_xr[tA][cA]);
        float s = xr.x + xr.y + xr.z + xr.w;
#pragma unroll
        for (int mk = 1; mk < 32; mk <<= 1) s += __shfl_xor(s, mk, 64);
        const float mu = s * (1.f / CC);
        float4 d;
        d.x = xr.x - mu; d.y = xr.y - mu; d.z = xr.z - mu; d.w = xr.w - mu;
        float v = d.x * d.x + d.y * d.y + d.z * d.z + d.w * d.w;
#pragma unroll
        for (int mk = 1; mk < 32; mk <<= 1) v += __shfl_xor(v, mk, 64);
        const float rs = rsqrtf(v * (1.f / CC) + 1e-5f);
        const float4 gv = *reinterpret_cast<const float4*>(g2 + cA);
        const float4 bv = *reinterpret_cast<const float4*>(b2v + cA);
        float4 y;
        y.x = d.x * rs * gv.x + bv.x;
        y.y = d.y * rs * gv.y + bv.y;
        y.z = d.z * rs * gv.z + bv.z;
        y.w = d.w * rs * gv.w + bv.w;
        *reinterpret_cast<float4*>(&s_ao[tA][cA]) = y;
    }
    __syncthreads();

    // ---- Phase P: MLP + residual -> x_final (bf16) ----
    {
        const float* wp = Wmlp + dV * CC;
        float a0 = 0.f, a1 = 0.f, a2 = 0.f, a3 = 0.f;
#pragma unroll 8
        for (int c = 0; c < CC; c += 4) {
            const float4 w = *reinterpret_cast<const float4*>(wp + c);
            a0 += dot4(w, *reinterpret_cast<const float4*>(&s_ao[tgV + 0][c]));
            a1 += dot4(w, *reinterpret_cast<const float4*>(&s_ao[tgV + 1][c]));
            a2 += dot4(w, *reinterpret_cast<const float4*>(&s_ao[tgV + 2][c]));
            a3 += dot4(w, *reinterpret_cast<const float4*>(&s_ao[tgV + 3][c]));
        }
        const float bm = bmlp[dV];
        xf_out[(size_t)(t0g + tgV + 0) * CC + dV] = f2b(s_xr[tgV + 0][dV] + a0 + bm);
        xf_out[(size_t)(t0g + tgV + 1) * CC + dV] = f2b(s_xr[tgV + 1][dV] + a1 + bm);
        xf_out[(size_t)(t0g + tgV + 2) * CC + dV] = f2b(s_xr[tgV + 2][dV] + a2 + bm);
        xf_out[(size_t)(t0g + tgV + 3) * CC + dV] = f2b(s_xr[tgV + 3][dV] + a3 + bm);
    }
}

// Wlm f32 -> bf16 (RNE), 8 elems/thread
__global__ __launch_bounds__(256)
void convert_kernel(const float* __restrict__ src,
                    unsigned short* __restrict__ dst, int n8)
{
    const int i = blockIdx.x * 256 + threadIdx.x;
    if (i >= n8) return;
    const float4 a = *reinterpret_cast<const float4*>(src + (size_t)i * 8);
    const float4 b = *reinterpret_cast<const float4*>(src + (size_t)i * 8 + 4);
    unsigned short v[8] = {f2b(a.x), f2b(a.y), f2b(a.z), f2b(a.w),
                           f2b(b.x), f2b(b.y), f2b(b.z), f2b(b.w)};
    *reinterpret_cast<uint4*>(dst + (size_t)i * 8) = *reinterpret_cast<uint4*>(v);
}

// logits = x_final @ Wlm^T via mfma_f32_16x16x32_bf16; f32 stores.
// Block = 4 waves side-by-side in N; wave tile = 64(M) x 64(N); K = 128 (4 k-steps).
__global__ __launch_bounds__(256)
void lm_kernel(const unsigned short* __restrict__ xf,
               const unsigned short* __restrict__ wlm,
               float* __restrict__ out)
{
    const int lane = threadIdx.x & 63;
    const int wid  = threadIdx.x >> 6;
    const int nl   = lane & 15;
    const int quad = lane >> 4;
    const int t0 = blockIdx.x * 64;                 // M: 64 m-tiles of 64 -> 4096
    const int v0 = blockIdx.y * 256 + wid * 64;     // N: 197 n-tiles of 256

    bf16x8 a[4][4];
    const unsigned short* abase = xf + (size_t)(t0 + nl) * CC + quad * 8;
#pragma unroll
    for (int mi = 0; mi < 4; mi++)
#pragma unroll
        for (int ks = 0; ks < 4; ks++)
            a[mi][ks] = *reinterpret_cast<const bf16x8*>(abase + (size_t)mi * 16 * CC + ks * 32);

    f32x4 acc[4][4];
#pragma unroll
    for (int mi = 0; mi < 4; mi++)
#pragma unroll
        for (int ni = 0; ni < 4; ni++)
            acc[mi][ni] = (f32x4){0.f, 0.f, 0.f, 0.f};

#pragma unroll
    for (int ni = 0; ni < 4; ni++) {
        const int vr = v0 + ni * 16 + nl;
        const int vrc = vr < VV ? vr : VV - 1;      // clamp (stores are masked)
        const unsigned short* bbase = wlm + (size_t)vrc * CC + quad * 8;
        bf16x8 b[4];
#pragma unroll
        for (int ks = 0; ks < 4; ks++)
            b[ks] = *reinterpret_cast<const bf16x8*>(bbase + ks * 32);
#pragma unroll
        for (int mi = 0; mi < 4; mi++)
#pragma unroll
            for (int ks = 0; ks < 4; ks++)
                acc[mi][ni] = __builtin_amdgcn_mfma_f32_16x16x32_bf16(a[mi][ks], b[ks],
                                                                      acc[mi][ni], 0, 0, 0);
    }

#pragma unroll
    for (int ni = 0; ni < 4; ni++) {
        const int col = v0 + ni * 16 + nl;
        if (col < VV) {
#pragma unroll
            for (int mi = 0; mi < 4; mi++) {
                const size_t rowb = (size_t)(t0 + mi * 16 + quad * 4) * VV + col;
#pragma unroll
                for (int r = 0; r < 4; r++)
                    out[rowb + (size_t)r * VV] = acc[mi][ni][r];
            }
        }
    }
}

extern "C" void kernel_launch(void* const* d_in, const int* in_sizes, int n_in,
                              void* d_out, int out_size, void* d_ws, size_t ws_size,
                              hipStream_t stream)
{
    const int*   ids    = (const int*)d_in[0];
    const float* emb    = (const float*)d_in[1];
    const float* router = (const float*)d_in[2];
    const float* k_ex   = (const float*)d_in[3];
    const float* v_ex   = (const float*)d_in[4];
    const float* st_k   = (const float*)d_in[5];
    const float* st_v   = (const float*)d_in[6];
    const float* kvg    = (const float*)d_in[7];
    const float* Wq     = (const float*)d_in[8];
    const float* Wo     = (const float*)d_in[9];
    const float* Wmlp   = (const float*)d_in[10];
    const float* bmlp   = (const float*)d_in[11];
    const float* g1     = (const float*)d_in[12];
    const float* b1     = (const float*)d_in[13];
    const float* g2     = (const float*)d_in[14];
    const float* b2v    = (const float*)d_in[15];
    const float* wlm    = (const float*)d_in[16];

    float* out      = (float*)d_out;
    float* gate_out = out + (size_t)BT * VV;              // logits first, then gate_logits

    unsigned short* xfbuf = (unsigned short*)d_ws;        // 4096*128 bf16 = 1 MB
    unsigned short* wlmb  = xfbuf + (size_t)BT * CC;      // 50257*128 bf16 = 12.9 MB

    token_kernel<<<dim3(BT / TB), dim3(256), 0, stream>>>(
        ids, emb, router, k_ex, v_ex, st_k, st_v, kvg,
        Wq, Wo, Wmlp, bmlp, g1, b1, g2, b2v, gate_out, xfbuf);

    const int n8 = (VV * CC) / 8;                         // 804112, exact
    convert_kernel<<<dim3((n8 + 255) / 256), dim3(256), 0, stream>>>(wlm, wlmb, n8);

    lm_kernel<<<dim3(64, 197), dim3(256), 0, stream>>>(xfbuf, wlmb, out);
}